// Round 1
// baseline (314.634 us; speedup 1.0000x reference)
//
#include <hip/hip_runtime.h>

// NeRF protein backbone builder.
// Round 1: correctness-first sequential kernel, one thread per chain.
// B=4096 chains, steps=511, each step places N, CA, C via dihedral geometry.

struct V3 { float x, y, z; };

__device__ __forceinline__ V3 vsub(V3 a, V3 b){ return {a.x-b.x, a.y-b.y, a.z-b.z}; }
__device__ __forceinline__ V3 vcross(V3 a, V3 b){
    return {a.y*b.z - a.z*b.y, a.z*b.x - a.x*b.z, a.x*b.y - a.y*b.x};
}
__device__ __forceinline__ float vdot(V3 a, V3 b){ return a.x*b.x + a.y*b.y + a.z*b.z; }
__device__ __forceinline__ V3 vunit(V3 a){
    float r = rsqrtf(vdot(a,a));
    return {a.x*r, a.y*r, a.z*r};
}

// d0 = -bond_length*cos(bond_angle); Ls = bond_length*sin(bond_angle)
__device__ __forceinline__ V3 place_dihedral(V3 a, V3 b, V3 c,
                                             float d0, float Ls, float tor){
    V3 ab = vsub(b, a);
    V3 bc = vunit(vsub(c, b));
    V3 n  = vunit(vcross(ab, bc));
    V3 nbc = vcross(n, bc);
    float sn, cs;
    __sincosf(tor, &sn, &cs);
    float d1 = Ls * cs;
    float d2 = Ls * sn;
    return { c.x + d0*bc.x + d1*nbc.x + d2*n.x,
             c.y + d0*bc.y + d1*nbc.y + d2*n.y,
             c.z + d0*bc.z + d1*nbc.z + d2*n.z };
}

// Constants (f64-derived, rounded to f32):
//   ANG_C_N  = 115deg: d0 = -1.34*cos = 0.56630847, Ls = 1.34*sin = 1.21445243
//   ANG_N_CA = 121deg: d0 = -1.46*cos = 0.75195559, Ls = 1.46*sin = 1.25146426
//   ANG_CA_C = 109deg: d0 = -1.54*cos = 0.50137496, Ls = 1.54*sin = 1.45609861

__global__ void nerf_seq_kernel(const float* __restrict__ phi,
                                const float* __restrict__ psi,
                                const float* __restrict__ omega,
                                float* __restrict__ out,
                                int B, int L, int steps){
    int b = blockIdx.x * blockDim.x + threadIdx.x;
    if (b >= B) return;

    V3 A  = {17.047f, 14.099f, 3.625f};   // N_INIT
    V3 Bv = {16.967f, 12.784f, 4.338f};   // CA_INIT
    V3 C  = {15.685f, 12.755f, 5.133f};   // C_INIT

    float* o = out + (size_t)b * 9u * (size_t)(steps + 1);
    o[0]=A.x;  o[1]=A.y;  o[2]=A.z;
    o[3]=Bv.x; o[4]=Bv.y; o[5]=Bv.z;
    o[6]=C.x;  o[7]=C.y;  o[8]=C.z;

    const float* pphi = phi   + (size_t)b * L;
    const float* ppsi = psi   + (size_t)b * L;
    const float* pome = omega + (size_t)b * L;

    for (int s = 0; s < steps; ++s){
        float t_psi = ppsi[s];
        float t_ome = pome[s];
        float t_phi = pphi[s + 1];

        V3 dn  = place_dihedral(A,  Bv, C,   0.56630847f, 1.21445243f, t_psi);
        V3 dca = place_dihedral(Bv, C,  dn,  0.75195559f, 1.25146426f, t_ome);
        V3 dc  = place_dihedral(C,  dn, dca, 0.50137496f, 1.45609861f, t_phi);

        float* os = o + 9u * (size_t)(s + 1);
        os[0]=dn.x;  os[1]=dn.y;  os[2]=dn.z;
        os[3]=dca.x; os[4]=dca.y; os[5]=dca.z;
        os[6]=dc.x;  os[7]=dc.y;  os[8]=dc.z;

        A = dn; Bv = dca; C = dc;
    }
}

extern "C" void kernel_launch(void* const* d_in, const int* in_sizes, int n_in,
                              void* d_out, int out_size, void* d_ws, size_t ws_size,
                              hipStream_t stream) {
    const float* phi   = (const float*)d_in[0];
    const float* psi   = (const float*)d_in[1];
    const float* omega = (const float*)d_in[2];
    float* out = (float*)d_out;

    // setup_inputs fixes L=512, max_length=512. Derive B and steps defensively
    // from the size info the harness gives us.
    const int L = 512;
    int B = in_sizes[0] / L;
    int steps = out_size / (9 * B) - 1;   // out_size = B * 9 * (steps+1)

    int block = 64;                        // spread 4096 threads over 64 CUs
    int grid = (B + block - 1) / block;
    nerf_seq_kernel<<<grid, block, 0, stream>>>(phi, psi, omega, out, B, L, steps);
}

// Round 2
// 157.337 us; speedup vs baseline: 1.9997x; 1.9997x over previous
//
#include <hip/hip_runtime.h>

// NeRF backbone builder — chunked rigid-transform scan.
// Phase 1: per (chain, chunk) compute chunk rigid transform from canonical triple.
// Phase 2: per chain, serial prefix-compose of chunk transforms.
// Phase 3: per (chain, chunk) seed world triple from prefix, replay steps, write out.

struct V3 { float x, y, z; };

__device__ __forceinline__ V3 vsub(V3 a, V3 b){ return {a.x-b.x, a.y-b.y, a.z-b.z}; }
__device__ __forceinline__ V3 vcross(V3 a, V3 b){
    return {a.y*b.z - a.z*b.y, a.z*b.x - a.x*b.z, a.x*b.y - a.y*b.x};
}
__device__ __forceinline__ float vdot(V3 a, V3 b){ return a.x*b.x + a.y*b.y + a.z*b.z; }
__device__ __forceinline__ V3 vunit(V3 a){
    float r = rsqrtf(vdot(a,a));
    return {a.x*r, a.y*r, a.z*r};
}

// Rigid transform: columns of R plus translation. p_out = c0*px + c1*py + c2*pz + t.
struct Xform { V3 c0, c1, c2, t; };

__device__ __forceinline__ V3 xrot(const Xform& X, V3 p){
    return { X.c0.x*p.x + X.c1.x*p.y + X.c2.x*p.z,
             X.c0.y*p.x + X.c1.y*p.y + X.c2.y*p.z,
             X.c0.z*p.x + X.c1.z*p.y + X.c2.z*p.z };
}
__device__ __forceinline__ V3 xapply(const Xform& X, V3 p){
    V3 r = xrot(X, p);
    return { r.x + X.t.x, r.y + X.t.y, r.z + X.t.z };
}
__device__ __forceinline__ Xform xcompose(const Xform& A, const Xform& B){ // A after B: A∘B
    Xform R;
    R.c0 = xrot(A, B.c0);
    R.c1 = xrot(A, B.c1);
    R.c2 = xrot(A, B.c2);
    R.t  = xapply(A, B.t);
    return R;
}

// Frame defined by triple (A,B,C): origin C, x=unit(C-B), z=unit(cross(B-A,x)), y=z×x... 
// matching reference: bc=unit(C-B), n=unit(cross(B-A,bc)), nbc=cross(n,bc).
__device__ __forceinline__ Xform frame_of(V3 A, V3 B, V3 C){
    V3 bc  = vunit(vsub(C, B));
    V3 n   = vunit(vcross(vsub(B, A), bc));
    V3 nbc = vcross(n, bc);
    return { bc, nbc, n, C };
}

// d0 = -L*cos(theta); Ls = L*sin(theta)
__device__ __forceinline__ V3 place_dihedral(V3 a, V3 b, V3 c,
                                             float d0, float Ls, float tor){
    V3 ab = vsub(b, a);
    V3 bc = vunit(vsub(c, b));
    V3 n  = vunit(vcross(ab, bc));
    V3 nbc = vcross(n, bc);
    float sn, cs;
    __sincosf(tor, &sn, &cs);
    float d1 = Ls * cs;
    float d2 = Ls * sn;
    return { c.x + d0*bc.x + d1*nbc.x + d2*n.x,
             c.y + d0*bc.y + d1*nbc.y + d2*n.y,
             c.z + d0*bc.z + d1*nbc.z + d2*n.z };
}

// Bond constants
#define D0_CN   0.56630847f
#define LS_CN   1.21445243f
#define D0_NCA  0.75195559f
#define LS_NCA  1.25146426f
#define D0_CAC  0.50137496f
#define LS_CAC  1.45609861f

// Canonical incoming triple in its own frame (derived; torsion-independent):
//   A0 = (-(1.46*D0_CAC + 1.54^2)/1.54, 1.46*LS_CAC/1.54, 0)
#define A0X (-2.0153295f)
#define A0Y ( 1.3804571f)

// World init triple
#define NIX 17.047f
#define NIY 14.099f
#define NIZ  3.625f
#define CAX 16.967f
#define CAY 12.784f
#define CAZ  4.338f
#define CIX 15.685f
#define CIY 12.755f
#define CIZ  5.133f

__device__ __forceinline__ void step3(V3& A, V3& B, V3& C,
                                      float tpsi, float tome, float tphi){
    V3 dn  = place_dihedral(A, B, C,  D0_CN,  LS_CN,  tpsi);
    V3 dca = place_dihedral(B, C, dn, D0_NCA, LS_NCA, tome);
    V3 dc  = place_dihedral(C, dn, dca, D0_CAC, LS_CAC, tphi);
    A = dn; B = dca; C = dc;
}

__device__ __forceinline__ void store_xform(float* p, const Xform& X){
    float4* q = (float4*)p;
    q[0] = make_float4(X.c0.x, X.c0.y, X.c0.z, X.c1.x);
    q[1] = make_float4(X.c1.y, X.c1.z, X.c2.x, X.c2.y);
    q[2] = make_float4(X.c2.z, X.t.x,  X.t.y,  X.t.z);
}
__device__ __forceinline__ Xform load_xform(const float* p){
    const float4* q = (const float4*)p;
    float4 a = q[0], b = q[1], c = q[2];
    Xform X;
    X.c0 = {a.x, a.y, a.z};
    X.c1 = {a.w, b.x, b.y};
    X.c2 = {b.z, b.w, c.x};
    X.t  = {c.y, c.z, c.w};
    return X;
}

// ---- Phase 1: chunk transforms ----
__global__ void nerf_phase1(const float* __restrict__ phi,
                            const float* __restrict__ psi,
                            const float* __restrict__ omega,
                            float* __restrict__ Mbuf,
                            int B, int L, int steps, int S, int nM){
    int tid = blockIdx.x * blockDim.x + threadIdx.x;
    if (tid >= B * nM) return;
    int b = tid / nM;
    int k = tid % nM;

    V3 A, Bv, C;
    if (k == 0){
        A = {NIX, NIY, NIZ}; Bv = {CAX, CAY, CAZ}; C = {CIX, CIY, CIZ};
    } else {
        A = {A0X, A0Y, 0.f}; Bv = {-1.54f, 0.f, 0.f}; C = {0.f, 0.f, 0.f};
    }
    int s0 = k * S;
    int s1 = min(steps, (k + 1) * S);
    const float* pphi = phi   + (size_t)b * L;
    const float* ppsi = psi   + (size_t)b * L;
    const float* pome = omega + (size_t)b * L;
    for (int s = s0; s < s1; ++s)
        step3(A, Bv, C, ppsi[s], pome[s], pphi[s + 1]);

    Xform M = frame_of(A, Bv, C);
    store_xform(Mbuf + (size_t)tid * 12u, M);
}

// ---- Phase 2: per-chain prefix compose ----
__global__ void nerf_phase2(const float* __restrict__ Mbuf,
                            float* __restrict__ Wbuf,
                            int B, int nM){
    int b = blockIdx.x * blockDim.x + threadIdx.x;
    if (b >= B) return;
    const float* m = Mbuf + (size_t)b * nM * 12u;
    float* w = Wbuf + (size_t)b * nM * 12u;
    Xform W = load_xform(m);
    store_xform(w, W);
    for (int k = 1; k < nM; ++k){
        Xform M = load_xform(m + (size_t)k * 12u);
        W = xcompose(W, M);
        store_xform(w + (size_t)k * 12u, W);
    }
}

// ---- Phase 3: expand chunks in world coords ----
__global__ void nerf_phase3(const float* __restrict__ phi,
                            const float* __restrict__ psi,
                            const float* __restrict__ omega,
                            const float* __restrict__ Wbuf,
                            float* __restrict__ out,
                            int B, int L, int steps, int S, int K, int nM){
    int tid = blockIdx.x * blockDim.x + threadIdx.x;
    if (tid >= B * K) return;
    int b = tid / K;
    int k = tid % K;

    float* o = out + (size_t)b * 9u * (size_t)(steps + 1);
    V3 A, Bv, C;
    if (k == 0){
        A = {NIX, NIY, NIZ}; Bv = {CAX, CAY, CAZ}; C = {CIX, CIY, CIZ};
        o[0]=A.x;  o[1]=A.y;  o[2]=A.z;
        o[3]=Bv.x; o[4]=Bv.y; o[5]=Bv.z;
        o[6]=C.x;  o[7]=C.y;  o[8]=C.z;
    } else {
        Xform W = load_xform(Wbuf + ((size_t)b * nM + (k - 1)) * 12u);
        A  = xapply(W, {A0X, A0Y, 0.f});
        Bv = xapply(W, {-1.54f, 0.f, 0.f});
        C  = W.t;  // xapply(W, origin)
    }
    int s0 = k * S;
    int s1 = min(steps, (k + 1) * S);
    const float* pphi = phi   + (size_t)b * L;
    const float* ppsi = psi   + (size_t)b * L;
    const float* pome = omega + (size_t)b * L;
    for (int s = s0; s < s1; ++s){
        step3(A, Bv, C, ppsi[s], pome[s], pphi[s + 1]);
        float* os = o + 9u * (size_t)(s + 1);
        os[0]=A.x;  os[1]=A.y;  os[2]=A.z;
        os[3]=Bv.x; os[4]=Bv.y; os[5]=Bv.z;
        os[6]=C.x;  os[7]=C.y;  os[8]=C.z;
    }
}

// ---- Fallback: round-1 sequential (used only if ws too small) ----
__global__ void nerf_seq_kernel(const float* __restrict__ phi,
                                const float* __restrict__ psi,
                                const float* __restrict__ omega,
                                float* __restrict__ out,
                                int B, int L, int steps){
    int b = blockIdx.x * blockDim.x + threadIdx.x;
    if (b >= B) return;
    V3 A  = {NIX, NIY, NIZ};
    V3 Bv = {CAX, CAY, CAZ};
    V3 C  = {CIX, CIY, CIZ};
    float* o = out + (size_t)b * 9u * (size_t)(steps + 1);
    o[0]=A.x;  o[1]=A.y;  o[2]=A.z;
    o[3]=Bv.x; o[4]=Bv.y; o[5]=Bv.z;
    o[6]=C.x;  o[7]=C.y;  o[8]=C.z;
    const float* pphi = phi   + (size_t)b * L;
    const float* ppsi = psi   + (size_t)b * L;
    const float* pome = omega + (size_t)b * L;
    for (int s = 0; s < steps; ++s){
        step3(A, Bv, C, ppsi[s], pome[s], pphi[s + 1]);
        float* os = o + 9u * (size_t)(s + 1);
        os[0]=A.x;  os[1]=A.y;  os[2]=A.z;
        os[3]=Bv.x; os[4]=Bv.y; os[5]=Bv.z;
        os[6]=C.x;  os[7]=C.y;  os[8]=C.z;
    }
}

extern "C" void kernel_launch(void* const* d_in, const int* in_sizes, int n_in,
                              void* d_out, int out_size, void* d_ws, size_t ws_size,
                              hipStream_t stream) {
    const float* phi   = (const float*)d_in[0];
    const float* psi   = (const float*)d_in[1];
    const float* omega = (const float*)d_in[2];
    float* out = (float*)d_out;

    const int L = 512;
    int B = in_sizes[0] / L;
    int steps = out_size / (9 * B) - 1;   // 511

    const int S = 16;
    int K = (steps + S - 1) / S;          // 32
    int nM = K - 1;                       // 31 transforms needed

    size_t needM = (size_t)B * nM * 12u * sizeof(float);
    size_t need = 2u * needM;
    if (ws_size < need || nM < 1) {
        int block = 64;
        int grid = (B + block - 1) / block;
        nerf_seq_kernel<<<grid, block, 0, stream>>>(phi, psi, omega, out, B, L, steps);
        return;
    }

    float* Mbuf = (float*)d_ws;
    float* Wbuf = Mbuf + (size_t)B * nM * 12u;

    int block = 256;
    int grid1 = (B * nM + block - 1) / block;
    nerf_phase1<<<grid1, block, 0, stream>>>(phi, psi, omega, Mbuf, B, L, steps, S, nM);

    int grid2 = (B + block - 1) / block;
    nerf_phase2<<<grid2, block, 0, stream>>>(Mbuf, Wbuf, B, nM);

    int grid3 = (B * K + block - 1) / block;
    nerf_phase3<<<grid3, block, 0, stream>>>(phi, psi, omega, Wbuf, out, B, L, steps, S, K, nM);
}

// Round 3
// 39.109 us; speedup vs baseline: 8.0450x; 4.0230x over previous
//
#include <hip/hip_runtime.h>

// NeRF backbone builder — fully fused wave-per-chain kernel.
// Lane k of the wave owns chunk k (S=8 steps). Pipeline within one wave:
//   1) compute chunk transform M_k from canonical triple (lane 0: world init)
//   2) in-wave inclusive scan (Hillis-Steele, 6 levels) -> prefix W_k
//   3) replay chunk steps in world coords seeded by W_{k-1}, stage atoms in LDS
//   4) cooperative float4 flush of the whole 18432B chain region (coalesced)

struct V3 { float x, y, z; };

__device__ __forceinline__ V3 vsub(V3 a, V3 b){ return {a.x-b.x, a.y-b.y, a.z-b.z}; }
__device__ __forceinline__ V3 vcross(V3 a, V3 b){
    return {a.y*b.z - a.z*b.y, a.z*b.x - a.x*b.z, a.x*b.y - a.y*b.x};
}
__device__ __forceinline__ float vdot(V3 a, V3 b){ return a.x*b.x + a.y*b.y + a.z*b.z; }
__device__ __forceinline__ V3 vunit(V3 a){
    float r = rsqrtf(vdot(a,a));
    return {a.x*r, a.y*r, a.z*r};
}

struct Xform { V3 c0, c1, c2, t; };  // p' = c0*px + c1*py + c2*pz + t

__device__ __forceinline__ V3 xrot(const Xform& X, V3 p){
    return { X.c0.x*p.x + X.c1.x*p.y + X.c2.x*p.z,
             X.c0.y*p.x + X.c1.y*p.y + X.c2.y*p.z,
             X.c0.z*p.x + X.c1.z*p.y + X.c2.z*p.z };
}
__device__ __forceinline__ V3 xapply(const Xform& X, V3 p){
    V3 r = xrot(X, p);
    return { r.x + X.t.x, r.y + X.t.y, r.z + X.t.z };
}
__device__ __forceinline__ Xform xcompose(const Xform& A, const Xform& B){ // A∘B (B first)
    Xform R;
    R.c0 = xrot(A, B.c0);
    R.c1 = xrot(A, B.c1);
    R.c2 = xrot(A, B.c2);
    R.t  = xapply(A, B.t);
    return R;
}

__device__ __forceinline__ Xform frame_of(V3 A, V3 B, V3 C){
    V3 bc  = vunit(vsub(C, B));
    V3 n   = vunit(vcross(vsub(B, A), bc));
    V3 nbc = vcross(n, bc);
    return { bc, nbc, n, C };
}

__device__ __forceinline__ Xform shfl_up_xf(const Xform& X, int d){
    Xform R;
    R.c0.x = __shfl_up(X.c0.x, d); R.c0.y = __shfl_up(X.c0.y, d); R.c0.z = __shfl_up(X.c0.z, d);
    R.c1.x = __shfl_up(X.c1.x, d); R.c1.y = __shfl_up(X.c1.y, d); R.c1.z = __shfl_up(X.c1.z, d);
    R.c2.x = __shfl_up(X.c2.x, d); R.c2.y = __shfl_up(X.c2.y, d); R.c2.z = __shfl_up(X.c2.z, d);
    R.t.x  = __shfl_up(X.t.x,  d); R.t.y  = __shfl_up(X.t.y,  d); R.t.z  = __shfl_up(X.t.z,  d);
    return R;
}

// Bond constants: d0 = -L*cos(theta), Ls = L*sin(theta)
#define D0_CN   0.56630847f
#define LS_CN   1.21445243f
#define D0_NCA  0.75195559f
#define LS_NCA  1.25146426f
#define D0_CAC  0.50137496f
#define LS_CAC  1.45609861f

// Canonical incoming triple in its own frame (torsion-independent; validated R2)
#define A0X (-2.0153295f)
#define A0Y ( 1.3804571f)

// World init triple
#define NIX 17.047f
#define NIY 14.099f
#define NIZ  3.625f
#define CAX 16.967f
#define CAY 12.784f
#define CAZ  4.338f
#define CIX 15.685f
#define CIY 12.755f
#define CIZ  5.133f

__device__ __forceinline__ V3 place_dihedral(V3 a, V3 b, V3 c,
                                             float d0, float Ls, float tor){
    V3 ab = vsub(b, a);
    V3 bc = vunit(vsub(c, b));
    V3 n  = vunit(vcross(ab, bc));
    V3 nbc = vcross(n, bc);
    float sn, cs;
    __sincosf(tor, &sn, &cs);
    float d1 = Ls * cs;
    float d2 = Ls * sn;
    return { c.x + d0*bc.x + d1*nbc.x + d2*n.x,
             c.y + d0*bc.y + d1*nbc.y + d2*n.y,
             c.z + d0*bc.z + d1*nbc.z + d2*n.z };
}

__device__ __forceinline__ void step3(V3& A, V3& B, V3& C,
                                      float tpsi, float tome, float tphi){
    V3 dn  = place_dihedral(A, B, C,  D0_CN,  LS_CN,  tpsi);
    V3 dca = place_dihedral(B, C, dn, D0_NCA, LS_NCA, tome);
    V3 dc  = place_dihedral(C, dn, dca, D0_CAC, LS_CAC, tphi);
    A = dn; B = dca; C = dc;
}

// ---- Fused kernel: one wave per chain (steps == 511, L == 512) ----
__global__ __launch_bounds__(64) void nerf_wave(const float* __restrict__ phi,
                                                const float* __restrict__ psi,
                                                const float* __restrict__ omega,
                                                float* __restrict__ out,
                                                int steps){
    const int L = 512;
    const int S = 8;
    int b = blockIdx.x;
    int k = threadIdx.x;              // chunk id 0..63
    int s0 = k * S;

    __shared__ float lds[4608];       // 9*(steps+1) floats = 18432 B

    const float* pphi = phi   + (size_t)b * L;
    const float* ppsi = psi   + (size_t)b * L;
    const float* pome = omega + (size_t)b * L;

    // Load this chunk's torsions once, keep in registers for both passes.
    float4 ps0 = ((const float4*)(ppsi + s0))[0];
    float4 ps1 = ((const float4*)(ppsi + s0))[1];
    float4 om0 = ((const float4*)(pome + s0))[0];
    float4 om1 = ((const float4*)(pome + s0))[1];
    float4 ph0 = ((const float4*)(pphi + s0))[0];
    float4 ph1 = ((const float4*)(pphi + s0))[1];
    float phi8 = __shfl_down(ph0.x, 1);   // phi[s0+8] from lane k+1 (unused at k=63)

    float tpsi[8] = {ps0.x, ps0.y, ps0.z, ps0.w, ps1.x, ps1.y, ps1.z, ps1.w};
    float tome[8] = {om0.x, om0.y, om0.z, om0.w, om1.x, om1.y, om1.z, om1.w};
    float tphi[8] = {ph0.y, ph0.z, ph0.w, ph1.x, ph1.y, ph1.z, ph1.w, phi8};

    // Pass 1: chunk transform from canonical triple (lane 0 from world init).
    V3 A, Bv, C;
    if (k == 0){
        A = {NIX, NIY, NIZ}; Bv = {CAX, CAY, CAZ}; C = {CIX, CIY, CIZ};
    } else {
        A = {A0X, A0Y, 0.f}; Bv = {-1.54f, 0.f, 0.f}; C = {0.f, 0.f, 0.f};
    }
    #pragma unroll
    for (int s = 0; s < 8; ++s){
        if (s0 + s < steps)
            step3(A, Bv, C, tpsi[s], tome[s], tphi[s]);
    }
    Xform W = frame_of(A, Bv, C);

    // Pass 2: in-wave inclusive scan, W_k = M_0 ∘ M_1 ∘ ... ∘ M_k.
    #pragma unroll
    for (int d = 1; d < 64; d <<= 1){
        Xform P = shfl_up_xf(W, d);
        if (k >= d) W = xcompose(P, W);
    }
    Xform Wp = shfl_up_xf(W, 1);      // W_{k-1} at lane k (lane 0 unused)

    // Pass 3: replay chunk in world coords, stage atoms in LDS.
    if (k == 0){
        A = {NIX, NIY, NIZ}; Bv = {CAX, CAY, CAZ}; C = {CIX, CIY, CIZ};
        lds[0]=A.x;  lds[1]=A.y;  lds[2]=A.z;
        lds[3]=Bv.x; lds[4]=Bv.y; lds[5]=Bv.z;
        lds[6]=C.x;  lds[7]=C.y;  lds[8]=C.z;
    } else {
        A  = xapply(Wp, {A0X, A0Y, 0.f});
        Bv = xapply(Wp, {-1.54f, 0.f, 0.f});
        C  = Wp.t;
    }
    #pragma unroll
    for (int s = 0; s < 8; ++s){
        if (s0 + s < steps){
            step3(A, Bv, C, tpsi[s], tome[s], tphi[s]);
            int base = (s0 + s + 1) * 9;
            lds[base+0]=A.x;  lds[base+1]=A.y;  lds[base+2]=A.z;
            lds[base+3]=Bv.x; lds[base+4]=Bv.y; lds[base+5]=Bv.z;
            lds[base+6]=C.x;  lds[base+7]=C.y;  lds[base+8]=C.z;
        }
    }
    __syncthreads();

    // Pass 4: coalesced flush — 1152 float4s, 18 iterations of lane-consecutive stores.
    float4* ol = (float4*)(out + (size_t)b * 4608u);
    const float4* ls = (const float4*)lds;
    #pragma unroll
    for (int i = 0; i < 18; ++i){
        int q = i * 64 + k;
        ol[q] = ls[q];
    }
}

// ---- Fallback: sequential one-thread-per-chain (general sizes) ----
__global__ void nerf_seq_kernel(const float* __restrict__ phi,
                                const float* __restrict__ psi,
                                const float* __restrict__ omega,
                                float* __restrict__ out,
                                int B, int L, int steps){
    int b = blockIdx.x * blockDim.x + threadIdx.x;
    if (b >= B) return;
    V3 A  = {NIX, NIY, NIZ};
    V3 Bv = {CAX, CAY, CAZ};
    V3 C  = {CIX, CIY, CIZ};
    float* o = out + (size_t)b * 9u * (size_t)(steps + 1);
    o[0]=A.x;  o[1]=A.y;  o[2]=A.z;
    o[3]=Bv.x; o[4]=Bv.y; o[5]=Bv.z;
    o[6]=C.x;  o[7]=C.y;  o[8]=C.z;
    const float* pphi = phi   + (size_t)b * L;
    const float* ppsi = psi   + (size_t)b * L;
    const float* pome = omega + (size_t)b * L;
    for (int s = 0; s < steps; ++s){
        step3(A, Bv, C, ppsi[s], pome[s], pphi[s + 1]);
        float* os = o + 9u * (size_t)(s + 1);
        os[0]=A.x;  os[1]=A.y;  os[2]=A.z;
        os[3]=Bv.x; os[4]=Bv.y; os[5]=Bv.z;
        os[6]=C.x;  os[7]=C.y;  os[8]=C.z;
    }
}

extern "C" void kernel_launch(void* const* d_in, const int* in_sizes, int n_in,
                              void* d_out, int out_size, void* d_ws, size_t ws_size,
                              hipStream_t stream) {
    const float* phi   = (const float*)d_in[0];
    const float* psi   = (const float*)d_in[1];
    const float* omega = (const float*)d_in[2];
    float* out = (float*)d_out;

    const int L = 512;
    int B = in_sizes[0] / L;
    int steps = out_size / (9 * B) - 1;

    if (steps == 511 && in_sizes[0] == B * 512) {
        nerf_wave<<<B, 64, 0, stream>>>(phi, psi, omega, out, steps);
    } else {
        int block = 64;
        int grid = (B + block - 1) / block;
        nerf_seq_kernel<<<grid, block, 0, stream>>>(phi, psi, omega, out, B, L, steps);
    }
}